// Round 5
// baseline (1605.313 us; speedup 1.0000x reference)
//
#include <hip/hip_runtime.h>
#include <hip/hip_bf16.h>
#include <cstdint>
#include <cstddef>

typedef __attribute__((ext_vector_type(8))) short sh8;
typedef __attribute__((ext_vector_type(4))) short sh4;
typedef __attribute__((ext_vector_type(4))) int ix4;
typedef __attribute__((ext_vector_type(16))) float floatx16;
typedef unsigned short ushort_t;

// ---------------------------------------------------------------------------
// ELL build: ell[out*S + k] = in  (slot unique per (out,k) -> no atomics)
// ---------------------------------------------------------------------------
__global__ void build_ell_kernel(const int* __restrict__ in_idx,
                                 const int* __restrict__ out_idx,
                                 int K, int S, int P, int n_in, int n_out,
                                 int* __restrict__ ell) {
  int i = blockIdx.x * 256 + threadIdx.x;
  if (i >= K * P) return;
  int vin = in_idx[i];
  int vout = out_idx[i];
  if (vin < n_in && vout < n_out) {
    ell[(size_t)vout * S + (i / P)] = vin;
  }
}

// ---------------------------------------------------------------------------
// Weight pack for 32x32x16 frags: W[k][ci][co] f32 -> Wp[k][ci/16][co][ci%16]
// ---------------------------------------------------------------------------
__global__ void pack_w_kernel(const float* __restrict__ W,
                              __hip_bfloat16* __restrict__ Wp,
                              int K, int CIN, int COUT) {
  long i = (long)blockIdx.x * 256 + threadIdx.x;
  long tot = (long)K * CIN * COUT;
  if (i >= tot) return;
  int co = (int)(i % COUT);
  long t = i / COUT;
  int ci = (int)(t % CIN);
  int k = (int)(t / CIN);
  float v = W[((long)k * CIN + ci) * COUT + co];
  Wp[(((long)k * (CIN / 16) + (ci >> 4)) * COUT + co) * 16 + (ci & 15)] =
      __float2bfloat16(v);
}

// zero bf16 buffer
__global__ void zero_bf16_kernel(__hip_bfloat16* __restrict__ p, long n) {
  long i = (long)blockIdx.x * 256 + threadIdx.x;
  if (i < n) p[i] = __float2bfloat16(0.f);
}

// conv0 weights: W0[125][1][64] -> Wp0[k/16][co][k%16], k padded to 128.
__global__ void pack_w0_kernel(const float* __restrict__ W,
                               __hip_bfloat16* __restrict__ Wp) {
  int i = blockIdx.x * 256 + threadIdx.x;
  if (i >= 128 * 64) return;
  int co = i & 63;
  int ki = i >> 6;
  float v = (ki < 125) ? W[ki * 64 + co] : 0.f;
  Wp[(((ki >> 4) * 64) + co) * 16 + (ki & 15)] = __float2bfloat16(v);
}

// feats f32 -> bf16 with one zero pad element at the end.
__global__ void f2bf_kernel(const float* __restrict__ x,
                            __hip_bfloat16* __restrict__ y, long n, long npad) {
  long i = (long)blockIdx.x * 256 + threadIdx.x;
  if (i >= npad) return;
  y[i] = __float2bfloat16(i < n ? x[i] : 0.f);
}

// Fixed-order sum of P partial buffers (deterministic).
__global__ void reduce_parts_kernel(const float* __restrict__ part, int P,
                                    long total, float* __restrict__ out) {
  long i = (long)blockIdx.x * 256 + threadIdx.x;
  if (i >= total) return;
  float s = 0.f;
  for (int p = 0; p < P; ++p) s += part[(size_t)p * total + i];
  out[i] = s;
}

// ---------------------------------------------------------------------------
// conv0: out[n0][64] = gatherA(x1ch, ell[*,128]) @ W0  via 32x32x16 MFMA.
// ---------------------------------------------------------------------------
__global__ __launch_bounds__(256, 2) void conv0_mfma_kernel(
    const ushort_t* __restrict__ xpad,   // [n0+1] bf16, [n0]=0
    const ushort_t* __restrict__ Wp0,    // [8][64][16]
    const int* __restrict__ ell,         // [n0][128]
    int n_out, float* __restrict__ out) {
  constexpr int STR = 152;
  __shared__ ushort_t xs[64 * STR];
  const int tid = threadIdx.x;
  const int lane = tid & 63;
  const int wv = tid >> 6;
  const int wm = wv & 1, wn = wv >> 1;
  const long m0 = (long)blockIdx.x * 64;
  const int row = tid >> 2;
  const int kk0 = (tid & 3) * 32;
  const long grow = m0 + row;

  if (grow < n_out) {
    const ix4* ep = (const ix4*)(ell + grow * 128 + kk0);
#pragma unroll
    for (int g = 0; g < 8; ++g) {
      ix4 e = ep[g];
      sh4 v;
#pragma unroll
      for (int j = 0; j < 4; ++j) {
        int ix = (e[j] < 0) ? n_out : e[j];
        v[j] = (short)xpad[ix];
      }
      *(sh4*)(&xs[row * STR + kk0 + g * 4]) = v;
    }
  } else {
    sh4 z = (sh4)(short)0;
#pragma unroll
    for (int g = 0; g < 8; ++g) *(sh4*)(&xs[row * STR + kk0 + g * 4]) = z;
  }
  __syncthreads();

  const int arow = wm * 32 + (lane & 31);
  const int koff = (lane >> 5) * 8;
  const int bcol = wn * 32 + (lane & 31);
  floatx16 acc = (floatx16)(0.0f);
#pragma unroll
  for (int kc = 0; kc < 8; ++kc) {
    sh8 a = *(const sh8*)(&xs[arow * STR + kc * 16 + koff]);
    sh8 b = *(const sh8*)(Wp0 + ((size_t)kc * 64 + bcol) * 16 + koff);
    acc = __builtin_amdgcn_mfma_f32_32x32x16_bf16(a, b, acc, 0, 0, 0);
  }
  const int lrow = (lane >> 5) * 4;
#pragma unroll
  for (int r = 0; r < 16; ++r) {
    long orow = m0 + wm * 32 + (r & 3) + 8 * (r >> 2) + lrow;
    if (orow < n_out) out[orow * 64 + bcol] = acc[r];
  }
}

// ---------------------------------------------------------------------------
// Main MFMA implicit-GEMM sparse conv.
// Block 256 = 4 waves (2M x 2N), BM=64 rows. Depth-3 register prefetch into a
// NBUF-ring of LDS buffers; 1 barrier/iter (NBUF=3) or 2 (NBUF=2).
// PAIR: CIN=64 inputs staged as 2 kernel-offsets side-by-side (CINE=128);
// weight pack layout is contiguous for pairs. blockIdx.y = iter partition
// (split-K) writing partials at out + y*n_out*COUT.
// ell==nullptr -> dense (in=row, valid while kk < kdense). xb pad row at n_in.
// ---------------------------------------------------------------------------
template <int CINE, int COUT, bool PAIR, int NBUF>
__global__ __launch_bounds__(256, 2) void conv_mfma_kernel(
    const ushort_t* __restrict__ xb, const ushort_t* __restrict__ Wp,
    const int* __restrict__ ell, int S, int KI, int KP, int kdense,
    int n_out, int n_in, float* __restrict__ out) {
  constexpr int KC = CINE / 16;     // 16-wide k-chunks per stage
  constexpr int NT = COUT / 64;     // 32-col frags per wave
  constexpr int STR = CINE + 24;
  constexpr int CH = CINE / 32;     // sh8 chunks per thread staging
  constexpr int RW = PAIR ? (CINE / 2) : CINE;  // input row width
  __shared__ ushort_t xs[NBUF][64 * STR];
  const int tid = threadIdx.x;
  const int lane = tid & 63;
  const int wv = tid >> 6;
  const int wm = wv & 1, wn = wv >> 1;
  const long m0 = (long)blockIdx.x * 64;
  const int srow = tid >> 2;
  const int scol = (tid & 3) * (CINE / 4);
  const int half = PAIR ? (scol >> 6) : 0;
  const int lcol = PAIR ? (scol & 63) : scol;
  const long grow = m0 + srow;

  const int i0 = blockIdx.y * KP;
  int i1 = i0 + KP;
  if (i1 > KI) i1 = KI;
  const int count = i1 - i0;
  out += (size_t)blockIdx.y * ((size_t)n_out * COUT);

  floatx16 acc[NT];
#pragma unroll
  for (int t = 0; t < NT; ++t) acc[t] = (floatx16)(0.0f);

  sh8 sreg0[CH], sreg1[CH], sreg2[CH];

  auto issue = [&](sh8 (&dst)[CH], int it) {
    const int kk = PAIR ? (2 * it + half) : it;
    int in = n_in;  // pad row (zeros)
    if (grow < n_out) {
      if (ell) {
        int e = ell[grow * (long)S + kk];
        if (e >= 0) in = e;
      } else if (kk < kdense) {
        in = (int)grow;
      }
    }
    const ushort_t* src = xb + (size_t)in * RW + lcol;
#pragma unroll
    for (int c = 0; c < CH; ++c) dst[c] = *(const sh8*)(src + c * 8);
  };
  auto commit = [&](ushort_t* buf, sh8 (&s)[CH]) {
    ushort_t* d = buf + srow * STR + scol;
#pragma unroll
    for (int c = 0; c < CH; ++c) *(sh8*)(d + c * 8) = s[c];
  };

  const int arow = wm * 32 + (lane & 31);
  const int koff = (lane >> 5) * 8;
  const int bcol = wn * (COUT / 2) + (lane & 31);

  auto mstep = [&](const ushort_t* buf, int it) {
    sh8 a[KC];
#pragma unroll
    for (int kc = 0; kc < KC; ++kc)
      a[kc] = *(const sh8*)(buf + arow * STR + kc * 16 + koff);
    const ushort_t* wk = Wp + ((size_t)it * KC * COUT + bcol) * 16 + koff;
#pragma unroll
    for (int t = 0; t < NT; ++t) {
#pragma unroll
      for (int kc = 0; kc < KC; ++kc) {
        sh8 b = *(const sh8*)(wk + ((size_t)kc * COUT + t * 32) * 16);
        acc[t] =
            __builtin_amdgcn_mfma_f32_32x32x16_bf16(a[kc], b, acc[t], 0, 0, 0);
      }
    }
  };

  if (NBUF == 3) {
    if (count > 0) issue(sreg0, i0);
    if (count > 1) issue(sreg1, i0 + 1);
    if (count > 2) issue(sreg2, i0 + 2);
    if (count > 0) commit(xs[0], sreg0);
    __syncthreads();
#define STEP3(J, BA, BB, SA, SB)                                               \
  {                                                                            \
    const int J_ = (J);                                                        \
    if (J_ < count) {                                                          \
      if (J_ + 1 < count) commit(xs[BB], SB);                                  \
      if (J_ + 3 < count) issue(SA, i0 + J_ + 3);                              \
      __syncthreads();                                                         \
      mstep(xs[BA], i0 + J_);                                                  \
    }                                                                          \
  }
    for (int j = 0; j < count; j += 3) {
      STEP3(j + 0, 0, 1, sreg0, sreg1)
      STEP3(j + 1, 1, 2, sreg1, sreg2)
      STEP3(j + 2, 2, 0, sreg2, sreg0)
    }
#undef STEP3
  } else {
    if (count > 0) issue(sreg0, i0);
    if (count > 1) issue(sreg1, i0 + 1);
    if (count > 0) commit(xs[0], sreg0);
    __syncthreads();
#define STEP2(J, BA, BB, SA, SB)                                               \
  {                                                                            \
    const int J_ = (J);                                                        \
    if (J_ < count) {                                                          \
      if (J_ + 1 < count) commit(xs[BB], SB);                                  \
      if (J_ + 2 < count) issue(SA, i0 + J_ + 2);                              \
      __syncthreads();                                                         \
      mstep(xs[BA], i0 + J_);                                                  \
      __syncthreads();                                                         \
    }                                                                          \
  }
    for (int j = 0; j < count; j += 2) {
      STEP2(j + 0, 0, 1, sreg0, sreg1)
      STEP2(j + 1, 1, 0, sreg1, sreg0)
    }
#undef STEP2
  }

  const int ccol = wn * (COUT / 2) + (lane & 31);
  const int lrowb = wm * 32 + (lane >> 5) * 4;
#pragma unroll
  for (int t = 0; t < NT; ++t) {
#pragma unroll
    for (int r = 0; r < 16; ++r) {
      long row = m0 + lrowb + (r & 3) + 8 * (r >> 2);
      if (row < n_out) out[row * COUT + ccol + t * 32] = acc[t][r];
    }
  }
}

// ---------------------------------------------------------------------------
// BN: deterministic two-pass stats + fused apply (residual/ReLU/bf16 + pad).
// ---------------------------------------------------------------------------
template <int C>
__global__ void bn_reduce1_kernel(const float* __restrict__ x, int n,
                                  float* __restrict__ part) {
  constexpr int RL = 256 / C;
  const int c = threadIdx.x % C;
  const int rl = threadIdx.x / C;
  float s = 0.f, ss = 0.f;
  for (long row = (long)blockIdx.x * RL + rl; row < n;
       row += (long)gridDim.x * RL) {
    float v = x[row * C + c];
    s += v;
    ss += v * v;
  }
  __shared__ float sh[512];
  sh[threadIdx.x] = s;
  sh[256 + threadIdx.x] = ss;
  __syncthreads();
  if (rl == 0) {
#pragma unroll
    for (int j = 1; j < RL; ++j) {
      s += sh[j * C + c];
      ss += sh[256 + j * C + c];
    }
    part[(size_t)blockIdx.x * 2 * C + c] = s;
    part[(size_t)blockIdx.x * 2 * C + C + c] = ss;
  }
}

template <int C>
__global__ void bn_reduce2_kernel(const float* __restrict__ part, int G,
                                  float* __restrict__ stats) {
  const int c = threadIdx.x;
  float s = 0.f, ss = 0.f;
  for (int g = 0; g < G; ++g) {
    s += part[(size_t)g * 2 * C + c];
    ss += part[(size_t)g * 2 * C + C + c];
  }
  stats[c] = s;
  stats[C + c] = ss;
}

template <int C, bool RELU, bool RES, bool WF32>
__global__ void bn_apply_kernel(const float* __restrict__ x,
                                const float* __restrict__ stats,
                                const float* __restrict__ gamma,
                                const float* __restrict__ beta,
                                const float* __restrict__ res,
                                long total, float inv_n,
                                float* __restrict__ out,
                                __hip_bfloat16* __restrict__ outb) {
  long i = (long)blockIdx.x * 256 + threadIdx.x;
  if (i >= total) {
    if (outb && i < total + C) outb[i] = __float2bfloat16(0.f);  // pad row
    return;
  }
  const int c = (int)(i % C);
  const float m = stats[c] * inv_n;
  const float var = stats[C + c] * inv_n - m * m;
  const float sc = rsqrtf(var + 1e-5f) * gamma[c];
  float v = (x[i] - m) * sc + beta[c];
  if (RES) v += res[i];
  if (RELU) v = fmaxf(v, 0.f);
  if (WF32) out[i] = v;
  if (outb) outb[i] = __float2bfloat16(v);
}

// ---------------------------------------------------------------------------

extern "C" void kernel_launch(void* const* d_in, const int* in_sizes, int n_in,
                              void* d_out, int out_size, void* d_ws,
                              size_t ws_size, hipStream_t stream) {
  const float* feats = (const float*)d_in[0];
  const float* W0  = (const float*)d_in[1];
  const float* g0  = (const float*)d_in[2];
  const float* b0  = (const float*)d_in[3];
  const float* Ws1 = (const float*)d_in[4];
  const float* gs1 = (const float*)d_in[5];
  const float* bs1 = (const float*)d_in[6];
  const float* Wa1 = (const float*)d_in[7];
  const float* ga1 = (const float*)d_in[8];
  const float* ba1 = (const float*)d_in[9];
  const float* Wb1 = (const float*)d_in[10];
  const float* gb1 = (const float*)d_in[11];
  const float* bb1 = (const float*)d_in[12];
  const float* Ws2 = (const float*)d_in[13];
  const float* gs2 = (const float*)d_in[14];
  const float* bs2 = (const float*)d_in[15];
  const float* Wa2 = (const float*)d_in[16];
  const float* ga2 = (const float*)d_in[17];
  const float* ba2 = (const float*)d_in[18];
  const float* Wb2 = (const float*)d_in[19];
  const float* gb2 = (const float*)d_in[20];
  const float* bb2 = (const float*)d_in[21];
  const float* Wd2 = (const float*)d_in[22];
  const float* gd2 = (const float*)d_in[23];
  const float* bd2 = (const float*)d_in[24];
  const float* Ws3 = (const float*)d_in[25];
  const float* gs3 = (const float*)d_in[26];
  const float* bs3 = (const float*)d_in[27];
  const float* Wa3 = (const float*)d_in[28];
  const float* ga3 = (const float*)d_in[29];
  const float* ba3 = (const float*)d_in[30];
  const float* Wb3 = (const float*)d_in[31];
  const float* gb3 = (const float*)d_in[32];
  const float* bb3 = (const float*)d_in[33];
  const float* Wd3 = (const float*)d_in[34];
  const float* gd3 = (const float*)d_in[35];
  const float* bd3 = (const float*)d_in[36];
  const int* im0  = (const int*)d_in[40];
  const int* om0  = (const int*)d_in[41];
  const int* ims1 = (const int*)d_in[42];
  const int* oms1 = (const int*)d_in[43];
  const int* imb1 = (const int*)d_in[44];
  const int* omb1 = (const int*)d_in[45];
  const int* ims2 = (const int*)d_in[46];
  const int* oms2 = (const int*)d_in[47];
  const int* imb2 = (const int*)d_in[48];
  const int* omb2 = (const int*)d_in[49];
  const int* ims3 = (const int*)d_in[50];
  const int* oms3 = (const int*)d_in[51];
  const int* imb3 = (const int*)d_in[52];
  const int* omb3 = (const int*)d_in[53];

  const int n0 = in_sizes[0];
  const int n1 = in_sizes[37] / 3;
  const int n2 = in_sizes[38] / 3;
  const int n3 = in_sizes[39] / 3;
  const int P0  = in_sizes[40] / 125;
  const int Ps1 = in_sizes[42] / 8;
  const int Pb1 = in_sizes[44] / 27;
  const int Ps2 = in_sizes[46] / 8;
  const int Pb2 = in_sizes[48] / 27;
  const int Ps3 = in_sizes[50] / 8;
  const int Pb3 = in_sizes[52] / 27;

  // ---- workspace carve ----
  char* w = (char*)d_ws;
  auto carve = [&](size_t bytes) {
    char* p = w;
    w += (bytes + 255) & ~(size_t)255;
    return p;
  };
  int* ellS = (int*)carve((size_t)n0 * 128 * sizeof(int));
  int* ellB = (int*)carve((size_t)n1 * 28 * sizeof(int));
  float* part = (float*)carve((size_t)256 * 512 * sizeof(float));
  float* stats = (float*)carve((size_t)512 * sizeof(float));
  size_t capE = (size_t)n0 * 64 + 256;  // + pad row
  float* buf1 = (float*)carve(capE * sizeof(float));
  float* buf2 = (float*)carve(capE * sizeof(float));
  float* buf3 = (float*)carve(capE * sizeof(float));
  __hip_bfloat16* bbA = (__hip_bfloat16*)carve(capE * 2);
  __hip_bfloat16* bbB = (__hip_bfloat16*)carve(capE * 2);
  __hip_bfloat16* bbC = (__hip_bfloat16*)carve(capE * 2);
  __hip_bfloat16* xfeat = (__hip_bfloat16*)carve(((size_t)n0 + 1) * 2);

  // ---- weight packing (padTo >= K slices; extra slices zeroed) ----
  auto pack = [&](const float* W, int K, int padTo, int cin, int cout) {
    __hip_bfloat16* Wp =
        (__hip_bfloat16*)carve((size_t)padTo * cin * cout * 2);
    if (padTo > K) {
      long z = (long)padTo * cin * cout;
      zero_bf16_kernel<<<(int)((z + 255) / 256), 256, 0, stream>>>(Wp, z);
    }
    long tot = (long)K * cin * cout;
    pack_w_kernel<<<(int)((tot + 255) / 256), 256, 0, stream>>>(W, Wp, K, cin,
                                                                cout);
    return Wp;
  };
  __hip_bfloat16* Wp0 = (__hip_bfloat16*)carve((size_t)128 * 64 * 2);
  pack_w0_kernel<<<32, 256, 0, stream>>>(W0, Wp0);
  __hip_bfloat16* Ps1p = pack(Ws1, 8, 8, 64, 64);
  __hip_bfloat16* Pa1p = pack(Wa1, 27, 28, 64, 64);
  __hip_bfloat16* Pb1p = pack(Wb1, 27, 28, 64, 64);
  __hip_bfloat16* Ps2p = pack(Ws2, 8, 8, 64, 64);
  __hip_bfloat16* Pd2p = pack(Wd2, 1, 2, 64, 128);
  __hip_bfloat16* Pa2p = pack(Wa2, 27, 28, 64, 128);
  __hip_bfloat16* Pb2p = pack(Wb2, 27, 27, 128, 128);
  __hip_bfloat16* Ps3p = pack(Ws3, 8, 8, 128, 128);
  __hip_bfloat16* Pd3p = pack(Wd3, 1, 1, 128, 256);
  __hip_bfloat16* Pa3p = pack(Wa3, 27, 27, 128, 256);
  __hip_bfloat16* Pb3p = pack(Wb3, 27, 27, 256, 256);

  // split-K partial buffer: all remaining workspace
  size_t used = (size_t)(w - (char*)d_ws);
  float* pbuf = (float*)w;
  size_t pcap = (ws_size > used) ? (ws_size - used) / sizeof(float) : 0;

  f2bf_kernel<<<(int)((n0 + 256) / 256), 256, 0, stream>>>(feats, xfeat, n0,
                                                           n0 + 1);

  auto buildEll = [&](int* ellbuf, const int* im, const int* om, int K, int S,
                      int P, int nin, int nout) {
    hipMemsetAsync(ellbuf, 0xFF, (size_t)nout * S * sizeof(int), stream);
    int tot = K * P;
    build_ell_kernel<<<(tot + 255) / 256, 256, 0, stream>>>(im, om, K, S, P,
                                                            nin, nout, ellbuf);
  };

  auto convm = [&](const __hip_bfloat16* xb, const __hip_bfloat16* Wp,
                   const int* ellp, int Kreal, int S, int nout, int nin,
                   int cin, int cout, float* outp) {
    int mblocks = (nout + 63) / 64;
    bool pair = (cin == 64);
    int KI = pair ? (Kreal + 1) / 2 : Kreal;
    int ks = 1;
    if (ellp && mblocks < 256 && KI > 1) {
      int desired = (512 + mblocks - 1) / mblocks;
      if (desired > 8) desired = 8;
      if (desired > KI) desired = KI;
      size_t need = (size_t)nout * cout;
      int fit = (need > 0) ? (int)(pcap / need) : 1;
      ks = desired < fit ? desired : fit;
      if (ks < 1) ks = 1;
    }
    int KP = (KI + ks - 1) / ks;
    int ksE = (KI + KP - 1) / KP;
    float* tgt = (ksE > 1) ? pbuf : outp;
    dim3 grid(mblocks, ksE);
#define CM_CASE(CI, CO, PAIRV, NB)                                             \
  else if (cin == CI && cout == CO) {                                          \
    conv_mfma_kernel<(CI == 64 ? 128 : CI), CO, PAIRV, NB>                     \
        <<<grid, 256, 0, stream>>>((const ushort_t*)xb, (const ushort_t*)Wp,   \
                                   ellp, S, KI, KP, Kreal, nout, nin, tgt);    \
  }
    if (false) {}
    CM_CASE(64, 64, true, 3)
    CM_CASE(64, 128, true, 3)
    CM_CASE(128, 128, false, 3)
    CM_CASE(128, 256, false, 3)
    CM_CASE(256, 256, false, 2)
#undef CM_CASE
    if (ksE > 1) {
      long total = (long)nout * cout;
      reduce_parts_kernel<<<(int)((total + 255) / 256), 256, 0, stream>>>(
          pbuf, ksE, total, outp);
    }
  };

  auto bn = [&](const float* x, int n, int C, const float* gamma,
                const float* beta, const float* res, bool relu, float* outp,
                __hip_bfloat16* outb) {
    const int G = 256;
    float invn = 1.0f / (float)n;
    long total = (long)n * C;
    int agrid = (int)((total + C + 255) / 256);
#define BN_CASE(CC)                                                            \
  else if (C == CC) {                                                          \
    bn_reduce1_kernel<CC><<<G, 256, 0, stream>>>(x, n, part);                  \
    bn_reduce2_kernel<CC><<<1, CC, 0, stream>>>(part, G, stats);               \
    if (res && relu)                                                           \
      bn_apply_kernel<CC, true, true, true><<<agrid, 256, 0, stream>>>(        \
          x, stats, gamma, beta, res, total, invn, outp, outb);                \
    else if (relu && outp)                                                     \
      bn_apply_kernel<CC, true, false, true><<<agrid, 256, 0, stream>>>(       \
          x, stats, gamma, beta, nullptr, total, invn, outp, outb);            \
    else if (relu)                                                             \
      bn_apply_kernel<CC, true, false, false><<<agrid, 256, 0, stream>>>(      \
          x, stats, gamma, beta, nullptr, total, invn, nullptr, outb);         \
    else                                                                       \
      bn_apply_kernel<CC, false, false, true><<<agrid, 256, 0, stream>>>(      \
          x, stats, gamma, beta, nullptr, total, invn, outp, outb);            \
  }
    if (false) {}
    BN_CASE(64)
    BN_CASE(128)
    BN_CASE(256)
#undef BN_CASE
  };

  float* y1 = (float*)d_out;
  float* y2 = y1 + (size_t)n1 * 64;
  float* y3 = y2 + (size_t)n2 * 128;

  // ---- stem: conv0 (k=125 -> GEMM over K=128) + BN ----
  buildEll(ellS, im0, om0, 125, 128, P0, n0, n0);
  conv0_mfma_kernel<<<(n0 + 63) / 64, 256, 0, stream>>>(
      (const ushort_t*)xfeat, (const ushort_t*)Wp0, ellS, n0, buf1);
  bn(buf1, n0, 64, g0, b0, nullptr, true, nullptr, bbA);            // x0

  // ---- level 1 ----
  buildEll(ellS, ims1, oms1, 8, 8, Ps1, n0, n1);
  convm(bbA, Ps1p, ellS, 8, 8, n1, n0, 64, 64, buf2);
  bn(buf2, n1, 64, gs1, bs1, nullptr, true, buf2, bbB);             // x1
  buildEll(ellB, imb1, omb1, 27, 28, Pb1, n1, n1);
  convm(bbB, Pa1p, ellB, 27, 28, n1, n1, 64, 64, buf3);
  bn(buf3, n1, 64, ga1, ba1, nullptr, true, nullptr, bbC);          // h1a
  convm(bbC, Pb1p, ellB, 27, 28, n1, n1, 64, 64, buf1);
  bn(buf1, n1, 64, gb1, bb1, buf2, true, y1, bbA);                  // y1

  // ---- level 2 ----
  buildEll(ellS, ims2, oms2, 8, 8, Ps2, n1, n2);
  convm(bbA, Ps2p, ellS, 8, 8, n2, n1, 64, 64, buf3);
  bn(buf3, n2, 64, gs2, bs2, nullptr, true, nullptr, bbB);          // x2
  convm(bbB, Pd2p, nullptr, 1, 2, n2, n2, 64, 128, buf1);
  bn(buf1, n2, 128, gd2, bd2, nullptr, false, buf1, nullptr);       // res2
  buildEll(ellB, imb2, omb2, 27, 28, Pb2, n2, n2);
  convm(bbB, Pa2p, ellB, 27, 28, n2, n2, 64, 128, buf2);
  bn(buf2, n2, 128, ga2, ba2, nullptr, true, nullptr, bbC);         // h2a
  convm(bbC, Pb2p, ellB, 27, 28, n2, n2, 128, 128, buf3);
  bn(buf3, n2, 128, gb2, bb2, buf1, true, y2, bbA);                 // y2

  // ---- level 3 ----
  buildEll(ellS, ims3, oms3, 8, 8, Ps3, n2, n3);
  convm(bbA, Ps3p, ellS, 8, 8, n3, n2, 128, 128, buf2);
  bn(buf2, n3, 128, gs3, bs3, nullptr, true, nullptr, bbB);         // x3
  convm(bbB, Pd3p, nullptr, 1, 1, n3, n3, 128, 256, buf1);
  bn(buf1, n3, 256, gd3, bd3, nullptr, false, buf1, nullptr);       // res3
  buildEll(ellB, imb3, omb3, 27, 28, Pb3, n3, n3);
  convm(bbB, Pa3p, ellB, 27, 28, n3, n3, 128, 256, buf3);
  bn(buf3, n3, 256, ga3, ba3, nullptr, true, nullptr, bbC);         // h3a
  convm(bbC, Pb3p, ellB, 27, 28, n3, n3, 256, 256, buf2);
  bn(buf2, n3, 256, gb3, bb3, buf1, true, y3, nullptr);             // y3
}

// Round 7
// 1537.420 us; speedup vs baseline: 1.0442x; 1.0442x over previous
//
#include <hip/hip_runtime.h>
#include <hip/hip_bf16.h>
#include <cstdint>
#include <cstddef>

typedef __attribute__((ext_vector_type(8))) short sh8;
typedef __attribute__((ext_vector_type(4))) short sh4;
typedef __attribute__((ext_vector_type(4))) int ix4;
typedef __attribute__((ext_vector_type(16))) float floatx16;
typedef unsigned short ushort_t;

__device__ __forceinline__ void glds16(const ushort_t* g, ushort_t* l) {
  __builtin_amdgcn_global_load_lds(
      (const __attribute__((address_space(1))) void*)g,
      (__attribute__((address_space(3))) void*)l, 16, 0, 0);
}

// ---------------------------------------------------------------------------
// ELL build: ell[out*S + k] = in  (slot unique per (out,k) -> no atomics)
// ---------------------------------------------------------------------------
__global__ void build_ell_kernel(const int* __restrict__ in_idx,
                                 const int* __restrict__ out_idx,
                                 int K, int S, int P, int n_in, int n_out,
                                 int* __restrict__ ell) {
  int i = blockIdx.x * 256 + threadIdx.x;
  if (i >= K * P) return;
  int vin = in_idx[i];
  int vout = out_idx[i];
  if (vin < n_in && vout < n_out) {
    ell[(size_t)vout * S + (i / P)] = vin;
  }
}

// ---------------------------------------------------------------------------
// Weight pack into per-virtual-iter LDS image: Wp[vk][lc 0..7][co][8] bf16.
// vk walks K*CSPLIT virtual iters of 64 input channels: k = vk/CSPLIT,
// ci = (vk%CSPLIT)*64 + vch.
// ---------------------------------------------------------------------------
__global__ void pack_u_kernel(const float* __restrict__ W,
                              __hip_bfloat16* __restrict__ Wp,
                              int K, int CSPLIT, int COUT, long total) {
  long i = (long)blockIdx.x * 256 + threadIdx.x;
  if (i >= total) return;
  int co = (int)(i % COUT);
  long t = i / COUT;
  int vch = (int)(t % 64);
  int vk = (int)(t / 64);
  int k = vk / CSPLIT;
  int ci = (vk % CSPLIT) * 64 + vch;
  int CIN = CSPLIT * 64;
  float v = (k < K) ? W[((long)k * CIN + ci) * COUT + co] : 0.f;
  Wp[(((long)vk * 8 + (vch >> 3)) * COUT + co) * 8 + (vch & 7)] =
      __float2bfloat16(v);
}

// conv0 weights: W0[125][1][64] -> Wp0[k/16][co][k%16], k padded to 128.
__global__ void pack_w0_kernel(const float* __restrict__ W,
                               __hip_bfloat16* __restrict__ Wp) {
  int i = blockIdx.x * 256 + threadIdx.x;
  if (i >= 128 * 64) return;
  int co = i & 63;
  int ki = i >> 6;
  float v = (ki < 125) ? W[ki * 64 + co] : 0.f;
  Wp[(((ki >> 4) * 64) + co) * 16 + (ki & 15)] = __float2bfloat16(v);
}

// feats f32 -> bf16 with one zero pad element at the end.
__global__ void f2bf_kernel(const float* __restrict__ x,
                            __hip_bfloat16* __restrict__ y, long n, long npad) {
  long i = (long)blockIdx.x * 256 + threadIdx.x;
  if (i >= npad) return;
  y[i] = __float2bfloat16(i < n ? x[i] : 0.f);
}

// Fixed-order sum of P partial buffers (deterministic).
__global__ void reduce_parts_kernel(const float* __restrict__ part, int P,
                                    long total, float* __restrict__ out) {
  long i = (long)blockIdx.x * 256 + threadIdx.x;
  if (i >= total) return;
  float s = 0.f;
  for (int p = 0; p < P; ++p) s += part[(size_t)p * total + i];
  out[i] = s;
}

// ---------------------------------------------------------------------------
// conv0: out[n0][64] = gatherA(x1ch, ell[*,128]) @ W0  via 32x32x16 MFMA.
// (LDS 19456 B; unchanged from round 4/5 — verified passing.)
// ---------------------------------------------------------------------------
__global__ __launch_bounds__(256, 2) void conv0_mfma_kernel(
    const ushort_t* __restrict__ xpad, const ushort_t* __restrict__ Wp0,
    const int* __restrict__ ell, int n_out, float* __restrict__ out) {
  constexpr int STR = 152;
  __shared__ ushort_t xs[64 * STR];
  const int tid = threadIdx.x;
  const int lane = tid & 63;
  const int wv = tid >> 6;
  const int wm = wv & 1, wn = wv >> 1;
  const long m0 = (long)blockIdx.x * 64;
  const int row = tid >> 2;
  const int kk0 = (tid & 3) * 32;
  const long grow = m0 + row;

  if (grow < n_out) {
    const ix4* ep = (const ix4*)(ell + grow * 128 + kk0);
#pragma unroll
    for (int g = 0; g < 8; ++g) {
      ix4 e = ep[g];
      sh4 v;
#pragma unroll
      for (int j = 0; j < 4; ++j) {
        int ix = (e[j] < 0) ? n_out : e[j];
        v[j] = (short)xpad[ix];
      }
      *(sh4*)(&xs[row * STR + kk0 + g * 4]) = v;
    }
  } else {
    sh4 z = (sh4)(short)0;
#pragma unroll
    for (int g = 0; g < 8; ++g) *(sh4*)(&xs[row * STR + kk0 + g * 4]) = z;
  }
  __syncthreads();

  const int arow = wm * 32 + (lane & 31);
  const int koff = (lane >> 5) * 8;
  const int bcol = wn * 32 + (lane & 31);
  floatx16 acc = (floatx16)(0.0f);
#pragma unroll
  for (int kc = 0; kc < 8; ++kc) {
    sh8 a = *(const sh8*)(&xs[arow * STR + kc * 16 + koff]);
    sh8 b = *(const sh8*)(Wp0 + ((size_t)kc * 64 + bcol) * 16 + koff);
    acc = __builtin_amdgcn_mfma_f32_32x32x16_bf16(a, b, acc, 0, 0, 0);
  }
  const int lrow = (lane >> 5) * 4;
#pragma unroll
  for (int r = 0; r < 16; ++r) {
    long orow = m0 + wm * 32 + (r & 3) + 8 * (r >> 2) + lrow;
    if (orow < n_out) out[orow * 64 + bcol] = acc[r];
  }
}

// ---------------------------------------------------------------------------
// Unified MFMA implicit-GEMM conv. 256 threads = 4 waves (2M x 2N).
// BM=64 rows, 64 output cols per block (z = col tile), VK=64 virtual input
// channels per iter (CSPLIT = CIN/64 slices per kernel offset).
// A and B staged to LDS via global_load_lds, double-buffered, counted
// vmcnt(4) pipeline, 2 raw barriers/iter. ell table in LDS. Total LDS 39936B.
// blockIdx.y = split-K partition writing partials at out + y*n_out*COfull.
// ---------------------------------------------------------------------------
template <int CSPLIT>
__global__ __launch_bounds__(256, 4) void conv_u_kernel(
    const ushort_t* __restrict__ xb, const ushort_t* __restrict__ Wp,
    const int* __restrict__ ell, int S, int KI, int KP, int kdense,
    int n_out, int n_in, int COfull, float* __restrict__ out) {
  __shared__ ushort_t Ab[2][4096];   // 64 rows x 64 vch (swizzled chunks)
  __shared__ ushort_t Bb[2][4096];   // 8 lc x 64 co x 8
  __shared__ int ells[64 * 28];
  constexpr int RW = CSPLIT * 64;    // input feature row width
  const int tid = threadIdx.x;
  const int lane = tid & 63;
  const int wv = tid >> 6;           // 0..3
  const int wm = wv >> 1, wn = wv & 1;
  const long m0 = (long)blockIdx.x * 64;
  const int colbase = blockIdx.z * 64;

  // ---- ell table -> LDS (pad-row index baked in) ----
  for (int idx = tid; idx < 64 * S; idx += 256) {
    int r = idx / S, k = idx - r * S;
    long grow = m0 + r;
    int v = -1;
    if (grow < n_out) {
      if (ell) v = ell[grow * (long)S + k];
      else if (k < kdense) v = (int)grow;
    }
    ells[idx] = (v < 0) ? n_in : v;
  }
  __syncthreads();

  const int i0 = blockIdx.y * KP;
  int cnt = KI - i0;
  if (cnt > KP) cnt = KP;
  out += (size_t)blockIdx.y * ((size_t)n_out * COfull);

  floatx16 acc = (floatx16)(0.0f);

  auto stage = [&](int vk, ushort_t* A, ushort_t* B) {
    const int sub = (CSPLIT == 1) ? 0 : (vk % CSPLIT);
    const int kq = (CSPLIT == 1) ? vk : (vk / CSPLIT);
    // A: 8 segs of 1KB (8 rows x 8 chunks); source-swizzled chunk c^ (r&7)
#pragma unroll
    for (int i = 0; i < 2; ++i) {
      const int s = wv * 2 + i;
      const int r = s * 8 + (lane >> 3);
      const int c = lane & 7;
      const int lc = c ^ (r & 7);
      const int e = ells[r * S + kq];
      glds16(xb + (size_t)e * RW + sub * 64 + lc * 8, A + s * 512 + lane * 8);
    }
    // B: 8 segs of 1KB (one lc row each), linear copy
    const ushort_t* wb = Wp + (size_t)vk * 8 * COfull * 8;
#pragma unroll
    for (int i = 0; i < 2; ++i) {
      const int s = wv * 2 + i;
      glds16(wb + ((size_t)s * COfull + colbase + lane) * 8,
             B + s * 512 + lane * 8);
    }
  };
  auto compute = [&](const ushort_t* A, const ushort_t* B) {
    const int r = wm * 32 + (lane & 31);
    const int h = lane >> 5;
    const int co = wn * 32 + (lane & 31);
    sh8 a[4];
#pragma unroll
    for (int kc = 0; kc < 4; ++kc) {
      const int lc = kc * 2 + h;
      const int pc = lc ^ (r & 7);
      a[kc] = *(const sh8*)(A + r * 64 + pc * 8);
    }
#pragma unroll
    for (int kc = 0; kc < 4; ++kc) {
      sh8 b = *(const sh8*)(B + ((kc * 2 + h) * 64 + co) * 8);
      acc = __builtin_amdgcn_mfma_f32_32x32x16_bf16(a[kc], b, acc, 0, 0, 0);
    }
  };

  stage(i0, Ab[0], Bb[0]);

#define CONV_ITER(J, PAR)                                                      \
  if ((J) < cnt) {                                                             \
    __builtin_amdgcn_s_barrier(); /* prev compute done: other bufs free */     \
    if ((J) + 1 < cnt) {                                                       \
      stage(i0 + (J) + 1, Ab[(PAR) ^ 1], Bb[(PAR) ^ 1]);                       \
      asm volatile("s_waitcnt vmcnt(4)" ::: "memory"); /* stage(J) landed */   \
    } else {                                                                   \
      asm volatile("s_waitcnt vmcnt(0)" ::: "memory");                         \
    }                                                                          \
    __builtin_amdgcn_s_barrier(); /* stage(J) visible to all waves */          \
    __builtin_amdgcn_sched_barrier(0);                                         \
    compute(Ab[PAR], Bb[PAR]);                                                 \
  }

  for (int j = 0; j < cnt; j += 2) {
    CONV_ITER(j, 0)
    CONV_ITER(j + 1, 1)
  }
#undef CONV_ITER

  // epilogue: C layout col=lane&31, row=(reg&3)+8*(reg>>2)+4*(lane>>5)
  const int ccol = colbase + wn * 32 + (lane & 31);
  const int rb = wm * 32 + (lane >> 5) * 4;
#pragma unroll
  for (int rr = 0; rr < 16; ++rr) {
    long row = m0 + rb + (rr & 3) + 8 * (rr >> 2);
    if (row < n_out) out[row * COfull + ccol] = acc[rr];
  }
}

// ---------------------------------------------------------------------------
// BN: deterministic two-pass stats + fused apply (residual/ReLU/bf16 + pad).
// ---------------------------------------------------------------------------
template <int C>
__global__ void bn_reduce1_kernel(const float* __restrict__ x, int n,
                                  float* __restrict__ part) {
  constexpr int RL = 256 / C;
  const int c = threadIdx.x % C;
  const int rl = threadIdx.x / C;
  float s = 0.f, ss = 0.f;
  for (long row = (long)blockIdx.x * RL + rl; row < n;
       row += (long)gridDim.x * RL) {
    float v = x[row * C + c];
    s += v;
    ss += v * v;
  }
  __shared__ float sh[512];
  sh[threadIdx.x] = s;
  sh[256 + threadIdx.x] = ss;
  __syncthreads();
  if (rl == 0) {
#pragma unroll
    for (int j = 1; j < RL; ++j) {
      s += sh[j * C + c];
      ss += sh[256 + j * C + c];
    }
    part[(size_t)blockIdx.x * 2 * C + c] = s;
    part[(size_t)blockIdx.x * 2 * C + C + c] = ss;
  }
}

template <int C>
__global__ void bn_reduce2_kernel(const float* __restrict__ part, int G,
                                  float* __restrict__ stats) {
  const int c = threadIdx.x;
  float s = 0.f, ss = 0.f;
  for (int g = 0; g < G; ++g) {
    s += part[(size_t)g * 2 * C + c];
    ss += part[(size_t)g * 2 * C + C + c];
  }
  stats[c] = s;
  stats[C + c] = ss;
}

template <int C, bool RELU, bool RES, bool WF32>
__global__ void bn_apply_kernel(const float* __restrict__ x,
                                const float* __restrict__ stats,
                                const float* __restrict__ gamma,
                                const float* __restrict__ beta,
                                const float* __restrict__ res,
                                long total, float inv_n,
                                float* __restrict__ out,
                                __hip_bfloat16* __restrict__ outb) {
  long i = (long)blockIdx.x * 256 + threadIdx.x;
  if (i >= total) {
    if (outb && i < total + C) outb[i] = __float2bfloat16(0.f);  // pad row
    return;
  }
  const int c = (int)(i % C);
  const float m = stats[c] * inv_n;
  const float var = stats[C + c] * inv_n - m * m;
  const float sc = rsqrtf(var + 1e-5f) * gamma[c];
  float v = (x[i] - m) * sc + beta[c];
  if (RES) v += res[i];
  if (RELU) v = fmaxf(v, 0.f);
  if (WF32) out[i] = v;
  if (outb) outb[i] = __float2bfloat16(v);
}

// ---------------------------------------------------------------------------

extern "C" void kernel_launch(void* const* d_in, const int* in_sizes, int n_in,
                              void* d_out, int out_size, void* d_ws,
                              size_t ws_size, hipStream_t stream) {
  const float* feats = (const float*)d_in[0];
  const float* W0  = (const float*)d_in[1];
  const float* g0  = (const float*)d_in[2];
  const float* b0  = (const float*)d_in[3];
  const float* Ws1 = (const float*)d_in[4];
  const float* gs1 = (const float*)d_in[5];
  const float* bs1 = (const float*)d_in[6];
  const float* Wa1 = (const float*)d_in[7];
  const float* ga1 = (const float*)d_in[8];
  const float* ba1 = (const float*)d_in[9];
  const float* Wb1 = (const float*)d_in[10];
  const float* gb1 = (const float*)d_in[11];
  const float* bb1 = (const float*)d_in[12];
  const float* Ws2 = (const float*)d_in[13];
  const float* gs2 = (const float*)d_in[14];
  const float* bs2 = (const float*)d_in[15];
  const float* Wa2 = (const float*)d_in[16];
  const float* ga2 = (const float*)d_in[17];
  const float* ba2 = (const float*)d_in[18];
  const float* Wb2 = (const float*)d_in[19];
  const float* gb2 = (const float*)d_in[20];
  const float* bb2 = (const float*)d_in[21];
  const float* Wd2 = (const float*)d_in[22];
  const float* gd2 = (const float*)d_in[23];
  const float* bd2 = (const float*)d_in[24];
  const float* Ws3 = (const float*)d_in[25];
  const float* gs3 = (const float*)d_in[26];
  const float* bs3 = (const float*)d_in[27];
  const float* Wa3 = (const float*)d_in[28];
  const float* ga3 = (const float*)d_in[29];
  const float* ba3 = (const float*)d_in[30];
  const float* Wb3 = (const float*)d_in[31];
  const float* gb3 = (const float*)d_in[32];
  const float* bb3 = (const float*)d_in[33];
  const float* Wd3 = (const float*)d_in[34];
  const float* gd3 = (const float*)d_in[35];
  const float* bd3 = (const float*)d_in[36];
  const int* im0  = (const int*)d_in[40];
  const int* om0  = (const int*)d_in[41];
  const int* ims1 = (const int*)d_in[42];
  const int* oms1 = (const int*)d_in[43];
  const int* imb1 = (const int*)d_in[44];
  const int* omb1 = (const int*)d_in[45];
  const int* ims2 = (const int*)d_in[46];
  const int* oms2 = (const int*)d_in[47];
  const int* imb2 = (const int*)d_in[48];
  const int* omb2 = (const int*)d_in[49];
  const int* ims3 = (const int*)d_in[50];
  const int* oms3 = (const int*)d_in[51];
  const int* imb3 = (const int*)d_in[52];
  const int* omb3 = (const int*)d_in[53];

  const int n0 = in_sizes[0];
  const int n1 = in_sizes[37] / 3;
  const int n2 = in_sizes[38] / 3;
  const int n3 = in_sizes[39] / 3;
  const int P0  = in_sizes[40] / 125;
  const int Ps1 = in_sizes[42] / 8;
  const int Pb1 = in_sizes[44] / 27;
  const int Ps2 = in_sizes[46] / 8;
  const int Pb2 = in_sizes[48] / 27;
  const int Ps3 = in_sizes[50] / 8;
  const int Pb3 = in_sizes[52] / 27;

  // ---- workspace carve ----
  char* w = (char*)d_ws;
  auto carve = [&](size_t bytes) {
    char* p = w;
    w += (bytes + 255) & ~(size_t)255;
    return p;
  };
  int* ellS = (int*)carve((size_t)n0 * 128 * sizeof(int));
  int* ellB = (int*)carve((size_t)n1 * 28 * sizeof(int));
  float* part = (float*)carve((size_t)256 * 512 * sizeof(float));
  float* stats = (float*)carve((size_t)512 * sizeof(float));
  size_t capE = (size_t)n0 * 64 + 512;  // + pad row
  float* buf1 = (float*)carve(capE * sizeof(float));
  float* buf2 = (float*)carve(capE * sizeof(float));
  float* buf3 = (float*)carve(capE * sizeof(float));
  __hip_bfloat16* bbA = (__hip_bfloat16*)carve(capE * 2);
  __hip_bfloat16* bbB = (__hip_bfloat16*)carve(capE * 2);
  __hip_bfloat16* bbC = (__hip_bfloat16*)carve(capE * 2);
  __hip_bfloat16* xfeat = (__hip_bfloat16*)carve(((size_t)n0 + 1) * 2);

  // ---- weight packing into LDS-image layout ----
  auto packu = [&](const float* W, int K, int cin, int cout) {
    int csplit = cin / 64;
    long tot = (long)K * csplit * 64 * cout;
    __hip_bfloat16* Wp = (__hip_bfloat16*)carve((size_t)tot * 2);
    pack_u_kernel<<<(int)((tot + 255) / 256), 256, 0, stream>>>(
        W, Wp, K, csplit, cout, tot);
    return Wp;
  };
  __hip_bfloat16* Wp0 = (__hip_bfloat16*)carve((size_t)128 * 64 * 2);
  pack_w0_kernel<<<32, 256, 0, stream>>>(W0, Wp0);
  __hip_bfloat16* Ps1p = packu(Ws1, 8, 64, 64);
  __hip_bfloat16* Pa1p = packu(Wa1, 27, 64, 64);
  __hip_bfloat16* Pb1p = packu(Wb1, 27, 64, 64);
  __hip_bfloat16* Ps2p = packu(Ws2, 8, 64, 64);
  __hip_bfloat16* Pd2p = packu(Wd2, 1, 64, 128);
  __hip_bfloat16* Pa2p = packu(Wa2, 27, 64, 128);
  __hip_bfloat16* Pb2p = packu(Wb2, 27, 128, 128);
  __hip_bfloat16* Ps3p = packu(Ws3, 8, 128, 128);
  __hip_bfloat16* Pd3p = packu(Wd3, 1, 128, 256);
  __hip_bfloat16* Pa3p = packu(Wa3, 27, 128, 256);
  __hip_bfloat16* Pb3p = packu(Wb3, 27, 256, 256);

  // split-K partial buffer: all remaining workspace
  size_t used = (size_t)(w - (char*)d_ws);
  float* pbuf = (float*)w;
  size_t pcap = (ws_size > used) ? (ws_size - used) / sizeof(float) : 0;

  f2bf_kernel<<<(int)((n0 + 256) / 256), 256, 0, stream>>>(feats, xfeat, n0,
                                                           n0 + 1);

  auto buildEll = [&](int* ellbuf, const int* im, const int* om, int K, int S,
                      int P, int nin, int nout) {
    hipMemsetAsync(ellbuf, 0xFF, (size_t)nout * S * sizeof(int), stream);
    int tot = K * P;
    build_ell_kernel<<<(tot + 255) / 256, 256, 0, stream>>>(im, om, K, S, P,
                                                            nin, nout, ellbuf);
  };

  auto convu = [&](const __hip_bfloat16* xb, const __hip_bfloat16* Wp,
                   const int* ellp, int S, int K, int kdense, int nout,
                   int nin, int cin, int cout, float* outp) {
    int csplit = cin / 64;
    int KIv = K * csplit;
    int cs = cout / 64;
    int mb = (nout + 63) / 64;
    int ks = 1;
    if (mb * cs < 256 && KIv > 1) {
      ks = (256 + mb * cs - 1) / (mb * cs);
      if (ks > 8) ks = 8;
      if (ks > KIv) ks = KIv;
      size_t need = (size_t)nout * cout;
      int fit = need ? (int)(pcap / need) : 1;
      if (ks > fit) ks = fit;
      if (ks < 1) ks = 1;
    }
    int KP = (KIv + ks - 1) / ks;
    int ksE = (KIv + KP - 1) / KP;
    float* tgt = (ksE > 1) ? pbuf : outp;
    dim3 grid(mb, ksE, cs);
#define CU_CASE(CSV)                                                           \
  else if (csplit == CSV) {                                                    \
    conv_u_kernel<CSV><<<grid, 256, 0, stream>>>(                              \
        (const ushort_t*)xb, (const ushort_t*)Wp, ellp, S, KIv, KP, kdense,    \
        nout, nin, cout, tgt);                                                 \
  }
    if (false) {}
    CU_CASE(1)
    CU_CASE(2)
    CU_CASE(4)
#undef CU_CASE
    if (ksE > 1) {
      long total = (long)nout * cout;
      reduce_parts_kernel<<<(int)((total + 255) / 256), 256, 0, stream>>>(
          pbuf, ksE, total, outp);
    }
  };

  auto bn = [&](const float* x, int n, int C, const float* gamma,
                const float* beta, const float* res, bool relu, float* outp,
                __hip_bfloat16* outb) {
    const int G = 256;
    float invn = 1.0f / (float)n;
    long total = (long)n * C;
    int agrid = (int)((total + C + 255) / 256);
#define BN_CASE(CC)                                                            \
  else if (C == CC) {                                                          \
    bn_reduce1_kernel<CC><<<G, 256, 0, stream>>>(x, n, part);                  \
    bn_reduce2_kernel<CC><<<1, CC, 0, stream>>>(part, G, stats);               \
    if (res && relu)                                                           \
      bn_apply_kernel<CC, true, true, true><<<agrid, 256, 0, stream>>>(        \
          x, stats, gamma, beta, res, total, invn, outp, outb);                \
    else if (relu && outp)                                                     \
      bn_apply_kernel<CC, true, false, true><<<agrid, 256, 0, stream>>>(       \
          x, stats, gamma, beta, nullptr, total, invn, outp, outb);            \
    else if (relu)                                                             \
      bn_apply_kernel<CC, true, false, false><<<agrid, 256, 0, stream>>>(      \
          x, stats, gamma, beta, nullptr, total, invn, nullptr, outb);         \
    else                                                                       \
      bn_apply_kernel<CC, false, false, true><<<agrid, 256, 0, stream>>>(      \
          x, stats, gamma, beta, nullptr, total, invn, outp, outb);            \
  }
    if (false) {}
    BN_CASE(64)
    BN_CASE(128)
    BN_CASE(256)
#undef BN_CASE
  };

  float* y1 = (float*)d_out;
  float* y2 = y1 + (size_t)n1 * 64;
  float* y3 = y2 + (size_t)n2 * 128;

  // ---- stem: conv0 (k=125 -> GEMM over K=128) + BN ----
  buildEll(ellS, im0, om0, 125, 128, P0, n0, n0);
  conv0_mfma_kernel<<<(n0 + 63) / 64, 256, 0, stream>>>(
      (const ushort_t*)xfeat, (const ushort_t*)Wp0, ellS, n0, buf1);
  bn(buf1, n0, 64, g0, b0, nullptr, true, nullptr, bbA);            // x0

  // ---- level 1 ----
  buildEll(ellS, ims1, oms1, 8, 8, Ps1, n0, n1);
  convu(bbA, Ps1p, ellS, 8, 8, 0, n1, n0, 64, 64, buf2);
  bn(buf2, n1, 64, gs1, bs1, nullptr, true, buf2, bbB);             // x1
  buildEll(ellB, imb1, omb1, 27, 28, Pb1, n1, n1);
  convu(bbB, Pa1p, ellB, 28, 27, 0, n1, n1, 64, 64, buf3);
  bn(buf3, n1, 64, ga1, ba1, nullptr, true, nullptr, bbC);          // h1a
  convu(bbC, Pb1p, ellB, 28, 27, 0, n1, n1, 64, 64, buf1);
  bn(buf1, n1, 64, gb1, bb1, buf2, true, y1, bbA);                  // y1

  // ---- level 2 ----
  buildEll(ellS, ims2, oms2, 8, 8, Ps2, n1, n2);
  convu(bbA, Ps2p, ellS, 8, 8, 0, n2, n1, 64, 64, buf3);
  bn(buf3, n2, 64, gs2, bs2, nullptr, true, nullptr, bbB);          // x2
  convu(bbB, Pd2p, nullptr, 1, 1, 1, n2, n2, 64, 128, buf1);
  bn(buf1, n2, 128, gd2, bd2, nullptr, false, buf1, nullptr);       // res2
  buildEll(ellB, imb2, omb2, 27, 28, Pb2, n2, n2);
  convu(bbB, Pa2p, ellB, 28, 27, 0, n2, n2, 64, 128, buf2);
  bn(buf2, n2, 128, ga2, ba2, nullptr, true, nullptr, bbC);         // h2a
  convu(bbC, Pb2p, ellB, 28, 27, 0, n2, n2, 128, 128, buf3);
  bn(buf3, n2, 128, gb2, bb2, buf1, true, y2, bbA);                 // y2

  // ---- level 3 ----
  buildEll(ellS, ims3, oms3, 8, 8, Ps3, n2, n3);
  convu(bbA, Ps3p, ellS, 8, 8, 0, n3, n2, 128, 128, buf2);
  bn(buf2, n3, 128, gs3, bs3, nullptr, true, nullptr, bbB);         // x3
  convu(bbB, Pd3p, nullptr, 1, 1, 1, n3, n3, 128, 256, buf1);
  bn(buf1, n3, 256, gd3, bd3, nullptr, false, buf1, nullptr);       // res3
  buildEll(ellB, imb3, omb3, 27, 28, Pb3, n3, n3);
  convu(bbB, Pa3p, ellB, 28, 27, 0, n3, n3, 128, 256, buf3);
  bn(buf3, n3, 256, ga3, ba3, nullptr, true, nullptr, bbC);         // h3a
  convu(bbC, Pb3p, ellB, 28, 27, 0, n3, n3, 256, 256, buf2);
  bn(buf2, n3, 256, gb3, bb3, buf1, true, y3, nullptr);             // y3
}